// Round 6
// baseline (205.716 us; speedup 1.0000x reference)
//
#include <hip/hip_runtime.h>
#include <stdint.h>

typedef __bf16 bf16_t;
typedef bf16_t bf16x8 __attribute__((ext_vector_type(8)));
typedef float f32x4 __attribute__((ext_vector_type(4)));
typedef float f32x16 __attribute__((ext_vector_type(16)));
typedef unsigned short us8 __attribute__((ext_vector_type(8)));
typedef unsigned short us4 __attribute__((ext_vector_type(4)));
typedef unsigned int u32x4 __attribute__((ext_vector_type(4)));

#define B_ 4
#define T_ 4096
#define C_ 1024
#define D_ 128

#define NCHUNK_PB 144   // per batch: sum over 32 q-tiles(128) of ceil((4jt+4)/16)
#define QSCALE 0.12751744f  // (1/sqrt(128)) * log2(e), folded into Q
#define M0 14.0f            // fixed softmax base (log2 domain); cancels in combine

__device__ __forceinline__ uint16_t f2bf(float f) {
    union { float f; uint32_t u; } v; v.f = f;
    uint32_t u = v.u;
    uint32_t r = (u + 0x7fffu + ((u >> 16) & 1u)) >> 16;
    return (uint16_t)r;
}

// round-half-up bf16 (2 VALU)
__device__ __forceinline__ uint16_t bfru(float f) {
    return (uint16_t)((__float_as_uint(f) + 0x8000u) >> 16);
}

__device__ __forceinline__ float bf2f(uint16_t u) {
    return __uint_as_float((uint32_t)u << 16);
}

// pack 2 f32 -> u32 of 2 bf16 (lo=a, hi=b); no builtin on gfx950 (T12 recipe)
__device__ __forceinline__ uint32_t cvtpk(float a, float b) {
    uint32_t r;
    asm("v_cvt_pk_bf16_f32 %0, %1, %2" : "=v"(r) : "v"(a), "v"(b));
    return r;
}

// v_permlane32_swap_b32: exchanges a.lanes[32:63] <-> b.lanes[0:31].
__device__ __forceinline__ void pl32swap(uint32_t& a, uint32_t& b) {
    asm("v_permlane32_swap_b32 %0, %1" : "+v"(a), "+v"(b));
}

// async global->LDS DMA, 16 B per lane. LDS dest = wave-uniform base + lane*16.
__device__ __forceinline__ void gload_lds16(const void* g, void* l) {
    __builtin_amdgcn_global_load_lds(
        (const __attribute__((address_space(1))) void*)g,
        (__attribute__((address_space(3))) void*)l, 16, 0, 0);
}

// ---------------------------------------------------------------------------
// Kernel 1: W[C,D] fp32 -> WT[w][n][k] bf16 (transposed), w in {q,k,v}
// ---------------------------------------------------------------------------
__global__ __launch_bounds__(256) void prep_w(const float* __restrict__ Wq,
                                              const float* __restrict__ Wk,
                                              const float* __restrict__ Wv,
                                              uint16_t* __restrict__ WT) {
    int idx = blockIdx.x * 256 + threadIdx.x;
    if (idx >= 3 * D_ * C_) return;
    int w   = idx / (D_ * C_);
    int rem = idx - w * (D_ * C_);
    int n   = rem / C_;
    int k   = rem - n * C_;
    const float* W = (w == 0) ? Wq : (w == 1) ? Wk : Wv;
    WT[idx] = f2bf(W[(size_t)k * D_ + n]);
}

// ---------------------------------------------------------------------------
// Kernel 2 (R9): FUSED QKV projection — unchanged from R9.
// ---------------------------------------------------------------------------
__global__ __launch_bounds__(512, 2) void qkv_fused(const float* __restrict__ x,
                                                    const uint16_t* __restrict__ WT,
                                                    uint16_t* __restrict__ qb,
                                                    uint16_t* __restrict__ kb,
                                                    uint16_t* __restrict__ vT) {
    __shared__ __align__(16) float    A_lds[2][64 * 32];        // 2 x 8 KB (fp32)
    __shared__ __align__(16) uint16_t W_lds[2][192 * 64];       // 2 x 24 KB (bf16)

    int tid  = threadIdx.x;
    int lane = tid & 63;
    int wave = tid >> 6;          // 0..7
    int quad = lane >> 4;
    int lx   = lane & 15;
    int wm   = wave >> 2;         // 0..1 : 32-row half
    int wn   = wave & 3;          // 0..3 : 32-col quarter

    int m0 = blockIdx.x * 64;

    auto issue_ab = [&](int bi, int k0) {
        {
            int row = wave * 8 + (lane >> 3);
            int gch = (lane & 7) ^ (row & 7);
            gload_lds16(x + (size_t)(m0 + row) * C_ + k0 + gch * 4,
                        &A_lds[bi][(wave * 8) * 32]);
        }
#pragma unroll
        for (int c = 0; c < 3; c++) {
            int fl  = wave * 24 + c * 8 + (lane >> 3);
            int gch = (lane & 7) ^ (fl & 7);
            int wsel = fl >> 6;
            int n    = 2 * (fl & 63) + (gch >> 2);
            gload_lds16(WT + (size_t)wsel * (D_ * C_) + (size_t)n * C_ + k0 + (gch & 3) * 8,
                        &W_lds[bi][(wave * 24 + c * 8) * 64]);
        }
    };

    f32x4 acc[3][2][2];
#pragma unroll
    for (int w = 0; w < 3; w++)
#pragma unroll
        for (int mf = 0; mf < 2; mf++)
#pragma unroll
            for (int nf = 0; nf < 2; nf++)
                acc[w][mf][nf] = (f32x4){0.f, 0.f, 0.f, 0.f};

    issue_ab(0, 0);
    int cur = 0;

    for (int k0 = 0; k0 < C_; k0 += 32) {
        __syncthreads();
        if (k0 + 32 < C_) issue_ab(cur ^ 1, k0 + 32);

        bf16x8 af[2];
#pragma unroll
        for (int mf = 0; mf < 2; mf++) {
            int arow = wm * 32 + mf * 16 + lx;
            const float* ar = &A_lds[cur][arow * 32];
            f32x4 a0 = *(const f32x4*)&ar[((2 * quad) ^ (arow & 7)) * 4];
            f32x4 a1 = *(const f32x4*)&ar[((2 * quad + 1) ^ (arow & 7)) * 4];
            u32x4 w = (u32x4){cvtpk(a0[0], a0[1]), cvtpk(a0[2], a0[3]),
                              cvtpk(a1[0], a1[1]), cvtpk(a1[2], a1[3])};
            af[mf] = *(bf16x8*)&w;
        }

#pragma unroll
        for (int wsel = 0; wsel < 3; wsel++)
#pragma unroll
            for (int nf = 0; nf < 2; nf++) {
                int n  = wn * 32 + nf * 16 + lx;
                int rp = n >> 1;
                int ch = ((n & 1) * 4 + quad) ^ (rp & 7);
                bf16x8 wf = *(const bf16x8*)&W_lds[cur][(wsel * 64 + rp) * 64 + ch * 8];
                acc[wsel][0][nf] = __builtin_amdgcn_mfma_f32_16x16x32_bf16(af[0], wf, acc[wsel][0][nf], 0, 0, 0);
                acc[wsel][1][nf] = __builtin_amdgcn_mfma_f32_16x16x32_bf16(af[1], wf, acc[wsel][1][nf], 0, 0, 0);
            }
        cur ^= 1;
    }

#pragma unroll
    for (int mf = 0; mf < 2; mf++) {
        int mrow0 = m0 + wm * 32 + mf * 16 + quad * 4;
        int batch = mrow0 >> 12;
        int t     = mrow0 & 4095;
#pragma unroll
        for (int nf = 0; nf < 2; nf++) {
            int n = wn * 32 + nf * 16 + lx;
#pragma unroll
            for (int r = 0; r < 4; r++) {
                qb[(size_t)(mrow0 + r) * D_ + n] = bfru(acc[0][mf][nf][r] * QSCALE);
                kb[(size_t)(mrow0 + r) * D_ + n] = bfru(acc[1][mf][nf][r]);
            }
            us4 pv;
#pragma unroll
            for (int r = 0; r < 4; r++) pv[r] = bfru(acc[2][mf][nf][r]);
            *(us4*)&vT[(size_t)batch * D_ * T_ + (size_t)n * T_ + t] = pv;
        }
    }
}

// ---------------------------------------------------------------------------
// Kernel 3 (R10): split-K flash attention, fixed-base softmax, T12 in-reg P.
// KVBLK 64 -> 32: LDS 64 KB -> 32 KB => 4 blocks/CU resident (16 waves/CU,
// 4/SIMD) instead of 2. All pipes were <25% busy with the costs stacked on
// one serial chain per block; doubling independent streams is the lever.
// Chunk stays 512 keys (16 tiles of 32): grid/part/ml/combine unchanged.
// Per-iter: 8 QK MFMA + 8 PV MFMA, 16-val softmax, 4 DMA ops/wave.
// ---------------------------------------------------------------------------
__global__ __launch_bounds__(256, 4) void attn(const uint16_t* __restrict__ qb,
                                               const uint16_t* __restrict__ kb,
                                               const uint16_t* __restrict__ vT,
                                               uint16_t* __restrict__ part,
                                               float* __restrict__ ml) {
    __shared__ __align__(16) uint16_t K_lds[2][32 * 128];    // 2 x 8192 B
    __shared__ __align__(16) uint16_t V_lds[2][128 * 32];    // 2 x 8192 B

    int tid  = threadIdx.x;
    int lane = tid & 63;
    int wave = tid >> 6;
    int q31  = lane & 31;   // q column (and key-row / d-row index in frags)
    int hi   = lane >> 5;   // kb group

    // decode blockIdx -> (batch, logical chunk L), longest chunks first.
    int batch = blockIdx.x & 3;
    int L     = NCHUNK_PB - 1 - (blockIdx.x >> 2);
    int a = 0;
    while (a < 7 && 2 * (a + 1) * (a + 2) <= L) a++;
    int rem   = L - 2 * a * (a + 1);
    int jt    = 4 * a + rem / (a + 1);
    int chunk = rem - (rem / (a + 1)) * (a + 1);
    int lidx  = batch * NCHUNK_PB + L;

    int q0     = jt * 128;
    int st0    = chunk * 16;                 // in 32-key tiles
    int ntiles = min(16, 4 * jt + 4 - st0);

    // issue one K+V 32-key tile into buffer bi via DMA.
    // K: 32 rows x 256B = 8 ops (2/wave, 4 rows/op). src chunk ^= row&7.
    // V: 128 rows x 64B = 8 ops (2/wave, 16 rows/op). src chunk ^= (row>>1)&3.
    auto issue_kv = [&](int bi, int tile) {
        int s0i = tile * 32;
        const uint16_t* kB = kb + (size_t)(batch * T_ + s0i) * D_;
#pragma unroll
        for (int j = 0; j < 2; j++) {
            int row = wave * 8 + j * 4 + (lane >> 4);
            int gch = (lane & 15) ^ (row & 7);
            gload_lds16(kB + (size_t)row * D_ + gch * 8,
                        &K_lds[bi][(wave * 8 + j * 4) * 128]);
        }
        const uint16_t* vB = vT + (size_t)batch * D_ * T_ + s0i;
#pragma unroll
        for (int j = 0; j < 2; j++) {
            int row = wave * 32 + j * 16 + (lane >> 2);
            int gch = (lane & 3) ^ ((row >> 1) & 3);
            gload_lds16(vB + (size_t)row * T_ + gch * 8,
                        &V_lds[bi][(wave * 32 + j * 16) * 32]);
        }
    };

    // Q fragments (B operand): lane = q + 32*kb holds d = kc*16 + kb*8 + j
    bf16x8 qf[8];
    {
        const uint16_t* qp = qb + (size_t)(batch * T_ + q0 + wave * 32 + q31) * D_ + hi * 8;
#pragma unroll
        for (int kc = 0; kc < 8; kc++) qf[kc] = *(const bf16x8*)(qp + kc * 16);
    }

    f32x16 o[4];
#pragma unroll
    for (int i = 0; i < 4; i++)
#pragma unroll
        for (int r = 0; r < 16; r++) o[i][r] = 0.f;
    float lsum = 0.f;

    issue_kv(0, st0);   // prologue prefetch
    int cur = 0;

    for (int it = 0; it < ntiles; it++) {
        int s0 = (st0 + it) * 32;
        // drains this wave's DMA (vmcnt(0) implicit) -> buf[cur] ready;
        // also guarantees all waves finished reading buf[cur^1] last iter.
        __syncthreads();
        if (it + 1 < ntiles) issue_kv(cur ^ 1, st0 + it + 1);

        // S^T = K Q^T (A = K-frag rows=32 keys, B = Q-frag)
        f32x16 st;
#pragma unroll
        for (int r = 0; r < 16; r++) st[r] = 0.f;
        __builtin_amdgcn_s_setprio(1);
#pragma unroll
        for (int kc = 0; kc < 8; kc++) {
            bf16x8 kf = *(const bf16x8*)&K_lds[cur][q31 * 128 + (((kc * 2 + hi) ^ (q31 & 7)) * 8)];
            st = __builtin_amdgcn_mfma_f32_32x32x16_bf16(kf, qf[kc], st, 0, 0, 0);
        }
        __builtin_amdgcn_s_setprio(0);

        // causal mask on diagonal-region tiles (wave-uniform branch)
        if (st0 + it >= 4 * jt) {
            int qg = q0 + wave * 32 + q31;
#pragma unroll
            for (int r = 0; r < 16; r++) {
                int sg = s0 + (r & 3) + 8 * (r >> 2) + 4 * hi;
                if (sg > qg) st[r] = -INFINITY;
            }
        }

        // p = exp2(s - M0); accumulate denominator per-lane (one q per lane)
#pragma unroll
        for (int r = 0; r < 16; r++) {
            st[r] = exp2f(st[r] - M0);
            lsum += st[r];
        }

        // build PV A-frags in-register: 8 cvt_pk + 4 permlane32_swap.
        bf16x8 pa[2];
        {
            uint32_t x0 = cvtpk(st[0],  st[1]);
            uint32_t x1 = cvtpk(st[2],  st[3]);
            uint32_t y0 = cvtpk(st[4],  st[5]);
            uint32_t y1 = cvtpk(st[6],  st[7]);
            pl32swap(x0, y0);
            pl32swap(x1, y1);
            u32x4 w0 = (u32x4){x0, x1, y0, y1};
            pa[0] = *(bf16x8*)&w0;
            uint32_t z0 = cvtpk(st[8],  st[9]);
            uint32_t z1 = cvtpk(st[10], st[11]);
            uint32_t t0 = cvtpk(st[12], st[13]);
            uint32_t t1 = cvtpk(st[14], st[15]);
            pl32swap(z0, t0);
            pl32swap(z1, t1);
            u32x4 w1 = (u32x4){z0, z1, t0, t1};
            pa[1] = *(bf16x8*)&w1;
        }

        // O += P V : A = pa[sb] (q x 16s), B = V-frag from vT layout [d][s32]
        __builtin_amdgcn_s_setprio(1);
#pragma unroll
        for (int sb = 0; sb < 2; sb++)
#pragma unroll
            for (int ntd = 0; ntd < 4; ntd++) {
                int row = ntd * 32 + q31;
                bf16x8 vf = *(const bf16x8*)&V_lds[cur][row * 32 + (((sb * 2 + hi) ^ ((row >> 1) & 3)) * 8)];
                o[ntd] = __builtin_amdgcn_mfma_f32_32x32x16_bf16(pa[sb], vf, o[ntd], 0, 0, 0);
            }
        __builtin_amdgcn_s_setprio(0);
        cur ^= 1;
    }

    // each q's denominator is split across lane and lane^32
    lsum += __shfl_xor(lsum, 32, 64);

    // write unnormalized partial (bf16) + l at the LOGICAL index.
    // O tile: col=lane&31 = d (within ntd*32), row = (r&3)+8*(r>>2)+4*hi = q
    uint16_t* pp = part + (size_t)lidx * (128 * 128);
#pragma unroll
    for (int ntd = 0; ntd < 4; ntd++)
#pragma unroll
        for (int r = 0; r < 16; r++) {
            int lrow = wave * 32 + (r & 3) + 8 * (r >> 2) + 4 * hi;
            pp[lrow * 128 + ntd * 32 + q31] = bfru(o[ntd][r]);
        }
    if (lane < 32)
        ml[(size_t)lidx * 128 + wave * 32 + q31] = lsum;
}

// ---------------------------------------------------------------------------
// Kernel 4: combine split-K partials: plain sums (fixed M0 cancels).
// Grid = (batch, jt128, col-half): 256 blocks; thread = (row, col-quarter).
// ---------------------------------------------------------------------------
__global__ __launch_bounds__(256) void combine(const uint16_t* __restrict__ part,
                                               const float* __restrict__ ml,
                                               float* __restrict__ out) {
    int bidx  = blockIdx.x;
    int half  = bidx & 1;
    int jt    = (bidx >> 1) & 31;
    int batch = bidx >> 6;
    int a     = jt >> 2;
    int base  = batch * NCHUNK_PB + 2 * a * (a + 1) + (jt - 4 * a) * (a + 1);
    int nch   = a + 1;

    int tid  = threadIdx.x;
    int lrow = tid >> 1;                 // 0..127
    int c0   = half * 64 + (tid & 1) * 32;

    float Lsum = 0.f;
    f32x4 acc[8];
#pragma unroll
    for (int i = 0; i < 8; i++) acc[i] = (f32x4){0.f, 0.f, 0.f, 0.f};

    for (int c = 0; c < nch; c++) {
        Lsum += ml[(size_t)(base + c) * 128 + lrow];
        const uint16_t* p = part + (size_t)(base + c) * (128 * 128) + lrow * 128 + c0;
#pragma unroll
        for (int i = 0; i < 4; i++) {
            us8 v = *(const us8*)(p + i * 8);
#pragma unroll
            for (int j = 0; j < 8; j++)
                acc[i * 2 + (j >> 2)][j & 3] += bf2f(v[j]);
        }
    }
    float inv = 1.f / Lsum;
    size_t row = (size_t)(batch * T_ + jt * 128 + lrow);
#pragma unroll
    for (int i = 0; i < 8; i++)
        *(f32x4*)(out + row * 128 + c0 + i * 4) = acc[i] * inv;
}

// ---------------------------------------------------------------------------
extern "C" void kernel_launch(void* const* d_in, const int* in_sizes, int n_in,
                              void* d_out, int out_size, void* d_ws, size_t ws_size,
                              hipStream_t stream) {
    const float* x  = (const float*)d_in[0];
    const float* Wq = (const float*)d_in[1];
    const float* Wk = (const float*)d_in[2];
    const float* Wv = (const float*)d_in[3];
    float* out = (float*)d_out;

    uint16_t* ws = (uint16_t*)d_ws;
    uint16_t* qb = ws;                                   // 16384*128 bf16
    uint16_t* kb = qb + (size_t)16384 * 128;
    uint16_t* vT = kb + (size_t)16384 * 128;
    uint16_t* WT = vT + (size_t)16384 * 128;             // 3*128*1024
    uint16_t* part = WT + (size_t)3 * D_ * C_;           // 576*128*128 bf16
    float* ml = (float*)(part + (size_t)4 * NCHUNK_PB * 128 * 128);  // 576*128 fp32

    prep_w<<<dim3((3 * D_ * C_ + 255) / 256), dim3(256), 0, stream>>>(Wq, Wk, Wv, WT);
    qkv_fused<<<dim3(16384 / 64), dim3(512), 0, stream>>>(x, WT, qb, kb, vT);
    attn<<<dim3(B_ * NCHUNK_PB), dim3(256), 0, stream>>>(qb, kb, vT, part, ml);
    combine<<<dim3(B_ * 32 * 2), dim3(256), 0, stream>>>(part, ml, out);
}

// Round 7
// 181.525 us; speedup vs baseline: 1.1333x; 1.1333x over previous
//
#include <hip/hip_runtime.h>
#include <stdint.h>

typedef __bf16 bf16_t;
typedef bf16_t bf16x8 __attribute__((ext_vector_type(8)));
typedef float f32x4 __attribute__((ext_vector_type(4)));
typedef float f32x16 __attribute__((ext_vector_type(16)));
typedef unsigned short us8 __attribute__((ext_vector_type(8)));
typedef unsigned short us4 __attribute__((ext_vector_type(4)));
typedef unsigned int u32x4 __attribute__((ext_vector_type(4)));

#define B_ 4
#define T_ 4096
#define C_ 1024
#define D_ 128

#define NCHUNK_PB 144   // per batch: sum over 32 q-tiles(128) of ceil((2jt+2)/8)
#define QSCALE 0.12751744f  // (1/sqrt(128)) * log2(e), folded into Q
#define M0 14.0f            // fixed softmax base (log2 domain); cancels in combine

__device__ __forceinline__ uint16_t f2bf(float f) {
    union { float f; uint32_t u; } v; v.f = f;
    uint32_t u = v.u;
    uint32_t r = (u + 0x7fffu + ((u >> 16) & 1u)) >> 16;
    return (uint16_t)r;
}

// round-half-up bf16 (2 VALU)
__device__ __forceinline__ uint16_t bfru(float f) {
    return (uint16_t)((__float_as_uint(f) + 0x8000u) >> 16);
}

__device__ __forceinline__ float bf2f(uint16_t u) {
    return __uint_as_float((uint32_t)u << 16);
}

// pack 2 f32 -> u32 of 2 bf16 (lo=a, hi=b); no builtin on gfx950 (T12 recipe)
__device__ __forceinline__ uint32_t cvtpk(float a, float b) {
    uint32_t r;
    asm("v_cvt_pk_bf16_f32 %0, %1, %2" : "=v"(r) : "v"(a), "v"(b));
    return r;
}

// v_permlane32_swap_b32: exchanges a.lanes[32:63] <-> b.lanes[0:31].
__device__ __forceinline__ void pl32swap(uint32_t& a, uint32_t& b) {
    asm("v_permlane32_swap_b32 %0, %1" : "+v"(a), "+v"(b));
}

// async global->LDS DMA, 16 B per lane. LDS dest = wave-uniform base + lane*16.
__device__ __forceinline__ void gload_lds16(const void* g, void* l) {
    __builtin_amdgcn_global_load_lds(
        (const __attribute__((address_space(1))) void*)g,
        (__attribute__((address_space(3))) void*)l, 16, 0, 0);
}

// ---------------------------------------------------------------------------
// Kernel 1: W[C,D] fp32 -> WT[w][n][k] bf16 (transposed), w in {q,k,v}
// ---------------------------------------------------------------------------
__global__ __launch_bounds__(256) void prep_w(const float* __restrict__ Wq,
                                              const float* __restrict__ Wk,
                                              const float* __restrict__ Wv,
                                              uint16_t* __restrict__ WT) {
    int idx = blockIdx.x * 256 + threadIdx.x;
    if (idx >= 3 * D_ * C_) return;
    int w   = idx / (D_ * C_);
    int rem = idx - w * (D_ * C_);
    int n   = rem / C_;
    int k   = rem - n * C_;
    const float* W = (w == 0) ? Wq : (w == 1) ? Wk : Wv;
    WT[idx] = f2bf(W[(size_t)k * D_ + n]);
}

// ---------------------------------------------------------------------------
// Kernel 2 (R11): wsel-SPLIT QKV projection. Block = one of {Q,K,V} x one
// 64-row M-tile -> grid 768 = 3 blocks/CU (was 256 = 1/CU, barrier-lockstep,
// serialization-bound at ~51us regardless of traffic: R4 3x-read == R9
// 1x-read). 3 independent streams/CU hide each other's per-iter DMA drain.
// x re-read 3x is the measured-free regime (L3 absorbs; traffic was not the
// binding constraint). Blocks sharing an x-tile are 256 apart in blockIdx ->
// same XCD under %8 round-robin -> x L2 co-located.
// LDS: A 2x8KB fp32 + W 2x8KB bf16 = 32KB. 4 waves (wm 0..1 x wn 0..1),
// 8 MFMA/wave/iter, BK=32, 32 iters. ~70 VGPR, no spill risk.
// ---------------------------------------------------------------------------
__global__ __launch_bounds__(256, 3) void qkv_split(const float* __restrict__ x,
                                                    const uint16_t* __restrict__ WT,
                                                    uint16_t* __restrict__ qb,
                                                    uint16_t* __restrict__ kb,
                                                    uint16_t* __restrict__ vT) {
    __shared__ __align__(16) float    A_lds[2][64 * 32];    // 2 x 8 KB (fp32)
    __shared__ __align__(16) uint16_t W_lds[2][128 * 32];   // 2 x 8 KB (bf16)

    int tid  = threadIdx.x;
    int lane = tid & 63;
    int wave = tid >> 6;          // 0..3
    int quad = lane >> 4;
    int lx   = lane & 15;
    int wm   = wave >> 1;         // 0..1 : 32-row half
    int wn   = wave & 1;          // 0..1 : 64-col half

    int bx   = blockIdx.x;
    int wsel = bx >> 8;           // 0..2 (Q/K/V)
    int m0   = (bx & 255) * 64;
    const uint16_t* Wp = WT + (size_t)wsel * (D_ * C_);

    // issue one BK=32 slice of A (64x32 f32) and W (128x32 bf16) into buf bi.
    // A: 128B rows (8 chunks); wave stages 16 rows via 2 ops. src chunk ^= row&7.
    // W: 64B rows (4 chunks); wave stages 32 rows via 2 ops. src chunk ^= (row>>1)&3.
    auto issue_ab = [&](int bi, int k0) {
#pragma unroll
        for (int j = 0; j < 2; j++) {
            int rbase = wave * 16 + j * 8;
            int row   = rbase + (lane >> 3);
            int gch   = (lane & 7) ^ (row & 7);
            gload_lds16(x + (size_t)(m0 + row) * C_ + k0 + gch * 4,
                        &A_lds[bi][rbase * 32]);
        }
#pragma unroll
        for (int j = 0; j < 2; j++) {
            int rbase = wave * 32 + j * 16;
            int row   = rbase + (lane >> 2);
            int gch   = (lane & 3) ^ ((row >> 1) & 3);
            gload_lds16(Wp + (size_t)row * C_ + k0 + gch * 8,
                        &W_lds[bi][rbase * 32]);
        }
    };

    f32x4 acc[2][4];
#pragma unroll
    for (int mf = 0; mf < 2; mf++)
#pragma unroll
        for (int nf = 0; nf < 4; nf++)
            acc[mf][nf] = (f32x4){0.f, 0.f, 0.f, 0.f};

    issue_ab(0, 0);   // prologue prefetch
    int cur = 0;

    for (int k0 = 0; k0 < C_; k0 += 32) {
        // drains this wave's DMA (vmcnt(0) implicit) -> buf[cur] ready;
        // also guarantees all waves finished reading buf[cur^1] last iter.
        __syncthreads();
        if (k0 + 32 < C_) issue_ab(cur ^ 1, k0 + 32);

        // A frags: fp32 from LDS (swizzled chunks), convert via cvt_pk.
        bf16x8 af[2];
#pragma unroll
        for (int mf = 0; mf < 2; mf++) {
            int arow = wm * 32 + mf * 16 + lx;
            const float* ar = &A_lds[cur][arow * 32];
            f32x4 a0 = *(const f32x4*)&ar[((2 * quad) ^ (arow & 7)) * 4];
            f32x4 a1 = *(const f32x4*)&ar[((2 * quad + 1) ^ (arow & 7)) * 4];
            u32x4 w = (u32x4){cvtpk(a0[0], a0[1]), cvtpk(a0[2], a0[3]),
                              cvtpk(a1[0], a1[1]), cvtpk(a1[2], a1[3])};
            af[mf] = *(bf16x8*)&w;
        }

#pragma unroll
        for (int nf = 0; nf < 4; nf++) {
            int n = wn * 64 + nf * 16 + lx;
            bf16x8 wf = *(const bf16x8*)&W_lds[cur][n * 32 + ((quad ^ ((n >> 1) & 3)) * 8)];
            acc[0][nf] = __builtin_amdgcn_mfma_f32_16x16x32_bf16(af[0], wf, acc[0][nf], 0, 0, 0);
            acc[1][nf] = __builtin_amdgcn_mfma_f32_16x16x32_bf16(af[1], wf, acc[1][nf], 0, 0, 0);
        }
        cur ^= 1;
    }

    // epilogue: C-layout row = quad*4+r, col = lx
#pragma unroll
    for (int mf = 0; mf < 2; mf++) {
        int mrow0 = m0 + wm * 32 + mf * 16 + quad * 4;
        int batch = mrow0 >> 12;
        int t     = mrow0 & 4095;
#pragma unroll
        for (int nf = 0; nf < 4; nf++) {
            int n = wn * 64 + nf * 16 + lx;
            if (wsel == 0) {
#pragma unroll
                for (int r = 0; r < 4; r++)
                    qb[(size_t)(mrow0 + r) * D_ + n] = bfru(acc[mf][nf][r] * QSCALE);
            } else if (wsel == 1) {
#pragma unroll
                for (int r = 0; r < 4; r++)
                    kb[(size_t)(mrow0 + r) * D_ + n] = bfru(acc[mf][nf][r]);
            } else {
                us4 pv;
#pragma unroll
                for (int r = 0; r < 4; r++) pv[r] = bfru(acc[mf][nf][r]);
                *(us4*)&vT[(size_t)batch * D_ * T_ + (size_t)n * T_ + t] = pv;
            }
        }
    }
}

// ---------------------------------------------------------------------------
// Kernel 3: split-K flash attention — REVERTED to the verified R9 version
// (53.2us, VGPR 100, 64KB LDS, 2 blocks/CU). R10's KVBLK=32 @ 4 blocks/CU
// spilled (demand ~145 regs > 128 cap) — infeasible, reverted.
// ---------------------------------------------------------------------------
__global__ __launch_bounds__(256, 2) void attn(const uint16_t* __restrict__ qb,
                                               const uint16_t* __restrict__ kb,
                                               const uint16_t* __restrict__ vT,
                                               uint16_t* __restrict__ part,
                                               float* __restrict__ ml) {
    __shared__ __align__(16) uint16_t K_lds[2][64 * 128];    // 2 x 16384 B
    __shared__ __align__(16) uint16_t V_lds[2][128 * 64];    // 2 x 16384 B

    int tid  = threadIdx.x;
    int lane = tid & 63;
    int wave = tid >> 6;
    int q31  = lane & 31;   // q column (and key-row / d-row index in frags)
    int hi   = lane >> 5;   // kb group

    // decode blockIdx -> (batch, logical chunk L), longest chunks first.
    int batch = blockIdx.x & 3;
    int L     = NCHUNK_PB - 1 - (blockIdx.x >> 2);
    int a = 0;
    while (a < 7 && 2 * (a + 1) * (a + 2) <= L) a++;
    int rem   = L - 2 * a * (a + 1);
    int jt    = 4 * a + rem / (a + 1);
    int chunk = rem - (rem / (a + 1)) * (a + 1);
    int lidx  = batch * NCHUNK_PB + L;

    int q0     = jt * 128;
    int st0    = chunk * 8;
    int ntiles = min(8, 2 * jt + 2 - st0);

    // issue one K+V 64-key tile into buffer bi via DMA.
    auto issue_kv = [&](int bi, int tile) {
        int s0i = tile * 64;
        const uint16_t* kB = kb + (size_t)(batch * T_ + s0i) * D_;
#pragma unroll
        for (int j = 0; j < 4; j++) {
            int row = wave * 16 + j * 4 + (lane >> 4);
            int gch = (lane & 15) ^ (row & 7);
            gload_lds16(kB + (size_t)row * D_ + gch * 8,
                        &K_lds[bi][(wave * 16 + j * 4) * 128]);
        }
        const uint16_t* vB = vT + (size_t)batch * D_ * T_ + s0i;
#pragma unroll
        for (int j = 0; j < 4; j++) {
            int row = wave * 32 + j * 8 + (lane >> 3);
            int gch = (lane & 7) ^ (row & 7);
            gload_lds16(vB + (size_t)row * T_ + gch * 8,
                        &V_lds[bi][(wave * 32 + j * 8) * 64]);
        }
    };

    // Q fragments (B operand): lane = q + 32*kb holds d = kc*16 + kb*8 + j
    bf16x8 qf[8];
    {
        const uint16_t* qp = qb + (size_t)(batch * T_ + q0 + wave * 32 + q31) * D_ + hi * 8;
#pragma unroll
        for (int kc = 0; kc < 8; kc++) qf[kc] = *(const bf16x8*)(qp + kc * 16);
    }

    f32x16 o[4];
#pragma unroll
    for (int i = 0; i < 4; i++)
#pragma unroll
        for (int r = 0; r < 16; r++) o[i][r] = 0.f;
    float lsum = 0.f;

    issue_kv(0, st0);   // prologue prefetch
    int cur = 0;

    for (int it = 0; it < ntiles; it++) {
        int s0 = (st0 + it) * 64;
        // drains this wave's DMA (vmcnt(0) implicit) -> buf[cur] ready;
        // also guarantees all waves finished reading buf[cur^1] last iter.
        __syncthreads();
        if (it + 1 < ntiles) issue_kv(cur ^ 1, st0 + it + 1);

        // S^T = K Q^T (A = K-frag, B = Q-frag), 2 s-tiles of 32
        f32x16 st[2];
#pragma unroll
        for (int nt = 0; nt < 2; nt++)
#pragma unroll
            for (int r = 0; r < 16; r++) st[nt][r] = 0.f;
        __builtin_amdgcn_s_setprio(1);
#pragma unroll
        for (int kc = 0; kc < 8; kc++)
#pragma unroll
            for (int nt = 0; nt < 2; nt++) {
                int row = nt * 32 + q31;
                bf16x8 kf = *(const bf16x8*)&K_lds[cur][row * 128 + (((kc * 2 + hi) ^ (row & 7)) * 8)];
                st[nt] = __builtin_amdgcn_mfma_f32_32x32x16_bf16(kf, qf[kc], st[nt], 0, 0, 0);
            }
        __builtin_amdgcn_s_setprio(0);

        // causal mask on diagonal-region tiles (wave-uniform branch)
        if (st0 + it >= 2 * jt) {
            int qg = q0 + wave * 32 + q31;
#pragma unroll
            for (int nt = 0; nt < 2; nt++)
#pragma unroll
                for (int r = 0; r < 16; r++) {
                    int sg = s0 + nt * 32 + (r & 3) + 8 * (r >> 2) + 4 * hi;
                    if (sg > qg) st[nt][r] = -INFINITY;
                }
        }

        // p = exp2(s - M0); accumulate denominator per-lane (one q per lane)
#pragma unroll
        for (int nt = 0; nt < 2; nt++)
#pragma unroll
            for (int r = 0; r < 16; r++) {
                st[nt][r] = exp2f(st[nt][r] - M0);
                lsum += st[nt][r];
            }

        // build PV A-frags in-register: 16 cvt_pk + 8 permlane32_swap.
        // pa[sb] reg j at lane(q,hi) = P[q][sb*16 + hi*8 + 2j, +2j+1]
        bf16x8 pa[4];
#pragma unroll
        for (int nt = 0; nt < 2; nt++) {
            uint32_t x0 = cvtpk(st[nt][0],  st[nt][1]);
            uint32_t x1 = cvtpk(st[nt][2],  st[nt][3]);
            uint32_t y0 = cvtpk(st[nt][4],  st[nt][5]);
            uint32_t y1 = cvtpk(st[nt][6],  st[nt][7]);
            pl32swap(x0, y0);
            pl32swap(x1, y1);
            u32x4 w0 = (u32x4){x0, x1, y0, y1};
            pa[2 * nt] = *(bf16x8*)&w0;
            uint32_t z0 = cvtpk(st[nt][8],  st[nt][9]);
            uint32_t z1 = cvtpk(st[nt][10], st[nt][11]);
            uint32_t t0 = cvtpk(st[nt][12], st[nt][13]);
            uint32_t t1 = cvtpk(st[nt][14], st[nt][15]);
            pl32swap(z0, t0);
            pl32swap(z1, t1);
            u32x4 w1 = (u32x4){z0, z1, t0, t1};
            pa[2 * nt + 1] = *(bf16x8*)&w1;
        }

        // O += P V : A = pa[sb] (q x 16s), B = V-frag from vT layout [d][s]
        __builtin_amdgcn_s_setprio(1);
#pragma unroll
        for (int sb = 0; sb < 4; sb++)
#pragma unroll
            for (int ntd = 0; ntd < 4; ntd++) {
                int row = ntd * 32 + q31;
                bf16x8 vf = *(const bf16x8*)&V_lds[cur][row * 64 + (((sb * 2 + hi) ^ (row & 7)) * 8)];
                o[ntd] = __builtin_amdgcn_mfma_f32_32x32x16_bf16(pa[sb], vf, o[ntd], 0, 0, 0);
            }
        __builtin_amdgcn_s_setprio(0);
        cur ^= 1;
    }

    // each q's denominator is split across lane and lane^32
    lsum += __shfl_xor(lsum, 32, 64);

    // write unnormalized partial (bf16) + l at the LOGICAL index.
    // O tile: col=lane&31 = d (within ntd*32), row = (r&3)+8*(r>>2)+4*hi = q
    uint16_t* pp = part + (size_t)lidx * (128 * 128);
#pragma unroll
    for (int ntd = 0; ntd < 4; ntd++)
#pragma unroll
        for (int r = 0; r < 16; r++) {
            int lrow = wave * 32 + (r & 3) + 8 * (r >> 2) + 4 * hi;
            pp[lrow * 128 + ntd * 32 + q31] = bfru(o[ntd][r]);
        }
    if (lane < 32)
        ml[(size_t)lidx * 128 + wave * 32 + q31] = lsum;
}

// ---------------------------------------------------------------------------
// Kernel 4: combine split-K partials: plain sums (fixed M0 cancels).
// Grid = (batch, jt128, col-half): 256 blocks; thread = (row, col-quarter).
// ---------------------------------------------------------------------------
__global__ __launch_bounds__(256) void combine(const uint16_t* __restrict__ part,
                                               const float* __restrict__ ml,
                                               float* __restrict__ out) {
    int bidx  = blockIdx.x;
    int half  = bidx & 1;
    int jt    = (bidx >> 1) & 31;
    int batch = bidx >> 6;
    int a     = jt >> 2;
    int base  = batch * NCHUNK_PB + 2 * a * (a + 1) + (jt - 4 * a) * (a + 1);
    int nch   = a + 1;

    int tid  = threadIdx.x;
    int lrow = tid >> 1;                 // 0..127
    int c0   = half * 64 + (tid & 1) * 32;

    float Lsum = 0.f;
    f32x4 acc[8];
#pragma unroll
    for (int i = 0; i < 8; i++) acc[i] = (f32x4){0.f, 0.f, 0.f, 0.f};

    for (int c = 0; c < nch; c++) {
        Lsum += ml[(size_t)(base + c) * 128 + lrow];
        const uint16_t* p = part + (size_t)(base + c) * (128 * 128) + lrow * 128 + c0;
#pragma unroll
        for (int i = 0; i < 4; i++) {
            us8 v = *(const us8*)(p + i * 8);
#pragma unroll
            for (int j = 0; j < 8; j++)
                acc[i * 2 + (j >> 2)][j & 3] += bf2f(v[j]);
        }
    }
    float inv = 1.f / Lsum;
    size_t row = (size_t)(batch * T_ + jt * 128 + lrow);
#pragma unroll
    for (int i = 0; i < 8; i++)
        *(f32x4*)(out + row * 128 + c0 + i * 4) = acc[i] * inv;
}

// ---------------------------------------------------------------------------
extern "C" void kernel_launch(void* const* d_in, const int* in_sizes, int n_in,
                              void* d_out, int out_size, void* d_ws, size_t ws_size,
                              hipStream_t stream) {
    const float* x  = (const float*)d_in[0];
    const float* Wq = (const float*)d_in[1];
    const float* Wk = (const float*)d_in[2];
    const float* Wv = (const float*)d_in[3];
    float* out = (float*)d_out;

    uint16_t* ws = (uint16_t*)d_ws;
    uint16_t* qb = ws;                                   // 16384*128 bf16
    uint16_t* kb = qb + (size_t)16384 * 128;
    uint16_t* vT = kb + (size_t)16384 * 128;
    uint16_t* WT = vT + (size_t)16384 * 128;             // 3*128*1024
    uint16_t* part = WT + (size_t)3 * D_ * C_;           // 576*128*128 bf16
    float* ml = (float*)(part + (size_t)4 * NCHUNK_PB * 128 * 128);  // 576*128 fp32

    prep_w<<<dim3((3 * D_ * C_ + 255) / 256), dim3(256), 0, stream>>>(Wq, Wk, Wv, WT);
    qkv_split<<<dim3(3 * 256), dim3(256), 0, stream>>>(x, WT, qb, kb, vT);
    attn<<<dim3(B_ * NCHUNK_PB), dim3(256), 0, stream>>>(qb, kb, vT, part, ml);
    combine<<<dim3(B_ * 32 * 2), dim3(256), 0, stream>>>(part, ml, out);
}